// Round 7
// baseline (386.752 us; speedup 1.0000x reference)
//
#include <hip/hip_runtime.h>

typedef unsigned short u16;
typedef short bf16x8 __attribute__((ext_vector_type(8)));
typedef float f32x4 __attribute__((ext_vector_type(4)));

// Problem constants: B=4, T=4096, D=1024, N=256, L=768, H=16, dh=64, TE=1024
// I/O dtype: float32 (per reference). Internal MFMA compute: bf16.

__device__ __forceinline__ float b2f(u16 u) {
  union { unsigned int u; float f; } x; x.u = ((unsigned int)u) << 16; return x.f;
}
__device__ __forceinline__ u16 f2b(float f) {
  union { float f; unsigned int u; } x; x.f = f;
  unsigned int u = x.u;
  return (u16)((u + 0x7FFFu + ((u >> 16) & 1u)) >> 16);  // RNE
}

// async global->LDS, 16B per lane. LDS dest = wave-uniform base + lane*16.
#define GLOAD_LDS16(g, l)                                                      \
  __builtin_amdgcn_global_load_lds(                                            \
      (const __attribute__((address_space(1))) unsigned int*)(g),              \
      (__attribute__((address_space(3))) unsigned int*)(l), 16, 0, 0)

// ---------------------------------------------------------------------------
// Fused 4-way transpose + f32->bf16: dst[C][R] = bf16(src[R][C]), C=1024.
// grid (32, 32, 4), block (32,8). z selects {Wq,Wk,Wv,Wo}; R in {1024,768}.
// Also zero-fills embo (8192 f32) so emb_k can atomicAdd split-K partials.
// ---------------------------------------------------------------------------
__global__ __launch_bounds__(256) void transpose4_k(
    const float* __restrict__ Wq, const float* __restrict__ Wk,
    const float* __restrict__ Wv, const float* __restrict__ Wo,
    u16* __restrict__ wqt, u16* __restrict__ wkt,
    u16* __restrict__ wvt, u16* __restrict__ wot,
    float* __restrict__ embo) {
  if (blockIdx.z == 0 && blockIdx.y == 0) {
    int idx = blockIdx.x * 256 + threadIdx.y * 32 + threadIdx.x;
    embo[idx] = 0.f;  // 32 blocks x 256 threads = 8192 = B*2D
  }
  const float* src; u16* dst; int R;
  switch (blockIdx.z) {
    case 0: src = Wq; dst = wqt; R = 1024; break;
    case 1: src = Wk; dst = wkt; R = 768;  break;
    case 2: src = Wv; dst = wvt; R = 768;  break;
    default: src = Wo; dst = wot; R = 1024; break;
  }
  int bx = blockIdx.x * 32, by = blockIdx.y * 32;
  if (by >= R) return;
  __shared__ float t[32][33];
  int x = threadIdx.x, y = threadIdx.y;
#pragma unroll
  for (int i = 0; i < 4; ++i)
    t[y * 4 + i][x] = src[(size_t)(by + y * 4 + i) * 1024 + bx + x];
  __syncthreads();
#pragma unroll
  for (int i = 0; i < 4; ++i)
    dst[(size_t)(bx + y * 4 + i) * R + by + x] = f2b(t[x][y * 4 + i]);
}

// ---------------------------------------------------------------------------
// Row LayerNorm, f32 in -> bf16 out. One block per row. C in {768, 1024}.
// ---------------------------------------------------------------------------
__global__ __launch_bounds__(256) void ln_k(const float* __restrict__ in,
                                            const float* __restrict__ g,
                                            const float* __restrict__ bta,
                                            u16* __restrict__ out, int C) {
  int row = blockIdx.x, tid = threadIdx.x;
  const float* p = in + (size_t)row * C;
  int i0 = tid * 4;
  bool act = i0 < C;
  float v0 = 0.f, v1 = 0.f, v2 = 0.f, v3 = 0.f;
  if (act) {
    float4 u = *(const float4*)(p + i0);
    v0 = u.x; v1 = u.y; v2 = u.z; v3 = u.w;
  }
  float s = v0 + v1 + v2 + v3;
  float q = v0 * v0 + v1 * v1 + v2 * v2 + v3 * v3;
  __shared__ float red[8];
#pragma unroll
  for (int m = 32; m; m >>= 1) { s += __shfl_xor(s, m); q += __shfl_xor(q, m); }
  if ((tid & 63) == 0) { red[tid >> 6] = s; red[4 + (tid >> 6)] = q; }
  __syncthreads();
  s = red[0] + red[1] + red[2] + red[3];
  q = red[4] + red[5] + red[6] + red[7];
  float invC = 1.0f / (float)C;
  float mu = s * invC;
  float rs = rsqrtf(q * invC - mu * mu + 1e-5f);
  if (act) {
    float4 ug = *(const float4*)(g + i0);
    float4 ub = *(const float4*)(bta + i0);
    ushort4 o;
    o.x = f2b((v0 - mu) * rs * ug.x + ub.x);
    o.y = f2b((v1 - mu) * rs * ug.y + ub.y);
    o.z = f2b((v2 - mu) * rs * ug.z + ub.z);
    o.w = f2b((v3 - mu) * rs * ug.w + ub.w);
    *(ushort4*)(out + (size_t)row * C + i0) = o;
  }
}

// ---------------------------------------------------------------------------
// Stylization (in-place safe): out = bf16( silu( LN(y)*(1+scale_b) + shift_b ) ).
// ---------------------------------------------------------------------------
__global__ __launch_bounds__(256) void style_k(const u16* __restrict__ y,
                                               const float* __restrict__ g,
                                               const float* __restrict__ bta,
                                               const float* __restrict__ embo,
                                               u16* __restrict__ out) {
  int row = blockIdx.x, tid = threadIdx.x;
  int b = row >> 12;  // T=4096
  const u16* p = y + (size_t)row * 1024;
  int i0 = tid * 4;
  ushort4 u = *(const ushort4*)(p + i0);
  float v0 = b2f(u.x), v1 = b2f(u.y), v2 = b2f(u.z), v3 = b2f(u.w);
  float s = v0 + v1 + v2 + v3;
  float q = v0 * v0 + v1 * v1 + v2 * v2 + v3 * v3;
  __shared__ float red[8];
#pragma unroll
  for (int m = 32; m; m >>= 1) { s += __shfl_xor(s, m); q += __shfl_xor(q, m); }
  if ((tid & 63) == 0) { red[tid >> 6] = s; red[4 + (tid >> 6)] = q; }
  __syncthreads();
  s = red[0] + red[1] + red[2] + red[3];
  q = red[4] + red[5] + red[6] + red[7];
  const float invC = 1.0f / 1024.0f;
  float mu = s * invC;
  float rs = rsqrtf(q * invC - mu * mu + 1e-5f);
  float4 ug = *(const float4*)(g + i0);
  float4 ub = *(const float4*)(bta + i0);
  float4 sc = *(const float4*)(embo + b * 2048 + i0);
  float4 sh = *(const float4*)(embo + b * 2048 + 1024 + i0);
  float h0 = ((v0 - mu) * rs * ug.x + ub.x) * (1.0f + sc.x) + sh.x;
  float h1 = ((v1 - mu) * rs * ug.y + ub.y) * (1.0f + sc.y) + sh.y;
  float h2 = ((v2 - mu) * rs * ug.z + ub.z) * (1.0f + sc.z) + sh.z;
  float h3 = ((v3 - mu) * rs * ug.w + ub.w) * (1.0f + sc.w) + sh.w;
  ushort4 o;
  o.x = f2b(h0 / (1.0f + __expf(-h0)));
  o.y = f2b(h1 / (1.0f + __expf(-h1)));
  o.z = f2b(h2 / (1.0f + __expf(-h2)));
  o.w = f2b(h3 / (1.0f + __expf(-h3)));
  *(ushort4*)(out + (size_t)row * 1024 + i0) = o;
}

// ---------------------------------------------------------------------------
// Split-K emb projection: embo[b][j] += sum_{i in split} silu(emb[b][i])*We[i][j]
// grid (8, 4, 8). embo pre-zeroed by transpose4_k; split 0 adds the bias.
// ---------------------------------------------------------------------------
__global__ __launch_bounds__(256) void emb_k(const float* __restrict__ emb,
                                             const float* __restrict__ We,
                                             const float* __restrict__ be,
                                             float* __restrict__ embo) {
  int b = blockIdx.y, tid = threadIdx.x;
  int j = blockIdx.x * 256 + tid;
  int i0 = blockIdx.z * 128;
  __shared__ float se[128];
  if (tid < 128) {
    float v = emb[b * 1024 + i0 + tid];
    se[tid] = v / (1.0f + __expf(-v));
  }
  __syncthreads();
  float acc = (blockIdx.z == 0) ? be[j] : 0.f;
#pragma unroll 8
  for (int i = 0; i < 128; ++i) acc += se[i] * We[(size_t)(i0 + i) * 2048 + j];
  atomicAdd(&embo[b * 2048 + j], acc);
}

// ---------------------------------------------------------------------------
// Fused K+V projections (one launch, 128 blocks concurrent): 128x128 tile,
// m97 structure. A = xfn (1024x768). blockIdx.z: 0 -> K = A@Wk^T + bk into
// kws (row-major); 1 -> V = A@Wv^T + bv into vtws (transposed V^T store).
// ---------------------------------------------------------------------------
__global__ __launch_bounds__(256) void kvproj_k(const u16* __restrict__ A,
                                                const u16* __restrict__ WkT,
                                                const u16* __restrict__ WvT,
                                                const float* __restrict__ bk_,
                                                const float* __restrict__ bv_,
                                                u16* __restrict__ Ck,
                                                u16* __restrict__ Cv) {
  const int K = 768, Nn = 1024;
  const u16* Bt = blockIdx.z ? WvT : WkT;
  const float* bias = blockIdx.z ? bv_ : bk_;
  __shared__ __align__(16) short As[128 * 64];
  __shared__ __align__(16) short Bs[128 * 64];
  int tid = threadIdx.x;
  int m0 = blockIdx.x * 128, n0 = blockIdx.y * 128;
  int wave = tid >> 6, lane = tid & 63;
  int l16 = lane & 15, quad = lane >> 4;
  int wm = (wave >> 1) * 64, wn = (wave & 1) * 64;

  f32x4 acc[4][4];
#pragma unroll
  for (int i = 0; i < 4; ++i)
#pragma unroll
    for (int j = 0; j < 4; ++j)
#pragma unroll
      for (int r = 0; r < 4; ++r) acc[i][j][r] = 0.f;

  for (int kt = 0; kt < K; kt += 64) {
#pragma unroll
    for (int p = 0; p < 4; ++p) {
      int c = p * 256 + tid;
      int r = c >> 3;
      int cd = ((c & 7) ^ (r & 7)) * 8;   // swizzled global column (shorts)
      int lb = (p * 256 + wave * 64) * 8; // wave's LDS chunk base (shorts)
      GLOAD_LDS16(A + (size_t)(m0 + r) * K + kt + cd, As + lb);
      GLOAD_LDS16(Bt + (size_t)(n0 + r) * K + kt + cd, Bs + lb);
    }
    __syncthreads();
#pragma unroll
    for (int ks = 0; ks < 2; ++ks) {
      int swz = ((ks * 4 + quad) ^ (l16 & 7)) * 8;
      bf16x8 af[4], bfr[4];
#pragma unroll
      for (int i = 0; i < 4; ++i)
        af[i] = *(const bf16x8*)&As[(wm + i * 16 + l16) * 64 + swz];
#pragma unroll
      for (int j = 0; j < 4; ++j)
        bfr[j] = *(const bf16x8*)&Bs[(wn + j * 16 + l16) * 64 + swz];
#pragma unroll
      for (int i = 0; i < 4; ++i)
#pragma unroll
        for (int j = 0; j < 4; ++j)
          acc[i][j] = __builtin_amdgcn_mfma_f32_16x16x32_bf16(af[i], bfr[j], acc[i][j], 0, 0, 0);
    }
    __syncthreads();
  }

#pragma unroll
  for (int j = 0; j < 4; ++j) {
    int col = n0 + wn + j * 16 + l16;
    float bv = bias[col];
#pragma unroll
    for (int i = 0; i < 4; ++i) {
      int row0 = m0 + wm + i * 16 + quad * 4;
#pragma unroll
      for (int r = 0; r < 4; ++r) {
        int row = row0 + r;
        float v = acc[i][j][r] + bv;
        if (blockIdx.z) {
          Cv[((size_t)((row >> 8) * 1024 + col)) * 256 + (row & 255)] = f2b(v);
        } else {
          Ck[(size_t)row * Nn + col] = f2b(v);
        }
      }
    }
  }
}

// ---------------------------------------------------------------------------
// 128x256-tile deep-pipelined GEMM, 2 BLOCKS/CU, for the two big
// 16384x1024x1024 GEMMs. BK=32, TRIPLE-buffered LDS (72 KiB/block), 8 waves
// (2M x 4N), per-wave output 64x64 (acc[4][4]).
// Per K-tile t: s_waitcnt vmcnt(3); s_barrier; stage t+2; 8 ds_read_b128;
// 16 MFMA (setprio 1). Counted vmcnt hits 0 only at the final tile.
// Epilogue: coalesced LDS-transpose in 64-row f32[64][256] chunks.
// mode 0: Cb = bf16(acc+bias);  mode 2: Cf = acc+bias+res (f32).
// ---------------------------------------------------------------------------
__global__ __launch_bounds__(512, 4) void gemm256_k(const u16* __restrict__ A,
                                                    const u16* __restrict__ Bt,
                                                    const float* __restrict__ bias,
                                                    const float* __restrict__ res,
                                                    u16* __restrict__ Cb,
                                                    float* __restrict__ Cf,
                                                    int M, int Nn, int K, int mode) {
  __shared__ __align__(16) short smem[36864];  // 72 KiB: [A0 A1 A2 | B0 B1 B2]
  short* AsB = smem;            // 3 x 4096 shorts (128x32 each)
  short* BsB = smem + 12288;    // 3 x 8192 shorts (256x32 each)
  int tid = threadIdx.x;
  int m0 = blockIdx.x * 128, n0 = blockIdx.y * 256;
  int wave = tid >> 6, lane = tid & 63;
  int l16 = lane & 15, quad = lane >> 4;
  int wm = (wave >> 2) * 64;   // 2 row-wave groups
  int wn = (wave & 3) * 64;    // 4 col-wave groups

  size_t offA;
  {
    int r = tid >> 2;
    int cg = (tid & 3) ^ ((r >> 1) & 3);
    offA = (size_t)(m0 + r) * K + cg * 8;
  }
  int ldsA = tid * 8;
  size_t offB[2];
  int ldsB[2];
#pragma unroll
  for (int p = 0; p < 2; ++p) {
    int c = p * 512 + tid;
    int r = c >> 2;
    int cg = (c & 3) ^ ((r >> 1) & 3);
    offB[p] = (size_t)(n0 + r) * K + cg * 8;
    ldsB[p] = c * 8;
  }

  int aoff[4], boff[4];
#pragma unroll
  for (int mi = 0; mi < 4; ++mi) {
    int R = wm + mi * 16 + l16;
    aoff[mi] = R * 32 + ((quad ^ ((R >> 1) & 3)) * 8);
  }
#pragma unroll
  for (int ni = 0; ni < 4; ++ni) {
    int R = wn + ni * 16 + l16;
    boff[ni] = R * 32 + ((quad ^ ((R >> 1) & 3)) * 8);
  }

  f32x4 acc[4][4];
#pragma unroll
  for (int i = 0; i < 4; ++i)
#pragma unroll
    for (int j = 0; j < 4; ++j)
#pragma unroll
      for (int r = 0; r < 4; ++r) acc[i][j][r] = 0.f;

#define STAGE(tt, bufc)                                                        \
  do {                                                                         \
    int kt_ = (tt) * 32;                                                       \
    GLOAD_LDS16(A + offA + kt_, AsB + (bufc) * 4096 + ldsA);                   \
    GLOAD_LDS16(Bt + offB[0] + kt_, BsB + (bufc) * 8192 + ldsB[0]);            \
    GLOAD_LDS16(Bt + offB[1] + kt_, BsB + (bufc) * 8192 + ldsB[1]);            \
  } while (0)

#define COMPUTE(curc)                                                          \
  do {                                                                         \
    const short* as_ = AsB + (curc) * 4096;                                    \
    const short* bs_ = BsB + (curc) * 8192;                                    \
    bf16x8 af[4], bfv[4];                                                      \
    _Pragma("unroll") for (int mi = 0; mi < 4; ++mi)                           \
        af[mi] = *(const bf16x8*)&as_[aoff[mi]];                               \
    _Pragma("unroll") for (int ni = 0; ni < 4; ++ni)                           \
        bfv[ni] = *(const bf16x8*)&bs_[boff[ni]];                              \
    __builtin_amdgcn_s_setprio(1);                                             \
    _Pragma("unroll") for (int mi = 0; mi < 4; ++mi)                           \
      _Pragma("unroll") for (int ni = 0; ni < 4; ++ni)                         \
        acc[mi][ni] = __builtin_amdgcn_mfma_f32_16x16x32_bf16(                 \
            af[mi], bfv[ni], acc[mi][ni], 0, 0, 0);                            \
    __builtin_amdgcn_s_setprio(0);                                             \
  } while (0)

  const int NT = K >> 5;  // 32 for K=1024
  STAGE(0, 0);
  STAGE(1, 1);

  int cur = 0;
  for (int t = 0; t < NT - 1; ++t) {
    asm volatile("s_waitcnt vmcnt(3)" ::: "memory");
    __builtin_amdgcn_s_barrier();
    asm volatile("" ::: "memory");
    if (t + 2 < NT) {
      int nb = cur + 2; if (nb >= 3) nb -= 3;
      STAGE(t + 2, nb);
    }
    COMPUTE(cur);
    cur = (cur == 2) ? 0 : cur + 1;
  }
  asm volatile("s_waitcnt vmcnt(0)" ::: "memory");
  __builtin_amdgcn_s_barrier();
  asm volatile("" ::: "memory");
  COMPUTE(cur);
#undef COMPUTE
#undef STAGE

  // coalesced epilogue via LDS transpose (f32[64][256] view, 2 chunks)
  float* eps = (float*)smem;
  float bv[4];
#pragma unroll
  for (int ni = 0; ni < 4; ++ni) bv[ni] = bias[n0 + wn + ni * 16 + l16];

#pragma unroll
  for (int half = 0; half < 2; ++half) {
    __syncthreads();
    if ((wave >> 2) == half) {
#pragma unroll
      for (int mi = 0; mi < 4; ++mi) {
#pragma unroll
        for (int ni = 0; ni < 4; ++ni) {
          int col = wn + ni * 16 + l16;
#pragma unroll
          for (int r = 0; r < 4; ++r) {
            int row = mi * 16 + quad * 4 + r;
            eps[row * 256 + (col ^ (((row >> 2) & 3) << 3))] =
                acc[mi][ni][r] + bv[ni];
          }
        }
      }
    }
    __syncthreads();
#pragma unroll
    for (int p = 0; p < 8; ++p) {
      int row = wave * 8 + p;
      int grow = m0 + half * 64 + row;
      int colb = (lane * 4) ^ (((row >> 2) & 3) << 3);
      f32x4 v = *(const f32x4*)&eps[row * 256 + colb];
      if (mode == 2) {
        float4 rv = ((const float4*)&res[(size_t)grow * Nn + n0])[lane];
        float4 o;
        o.x = v[0] + rv.x; o.y = v[1] + rv.y;
        o.z = v[2] + rv.z; o.w = v[3] + rv.w;
        ((float4*)&Cf[(size_t)grow * Nn + n0])[lane] = o;
      } else {
        ushort4 o;
        o.x = f2b(v[0]); o.y = f2b(v[1]); o.z = f2b(v[2]); o.w = f2b(v[3]);
        ((ushort4*)&Cb[(size_t)grow * Nn + n0])[lane] = o;
      }
    }
  }
}

// ---------------------------------------------------------------------------
// Cross-attention: per (b,h), 64 Q-rows per block (4 waves x 16 rows).
// LDS = 32 KB (K tile, reused as P) -> 5 blocks/CU, 20 waves/CU.
// K staged via global_load_lds (pre-swizzled source, linear dest).
// V is NOT staged: PV B-fragments read directly from global VT (L2-resident,
// 32 KB per (b,h) reused by 64 blocks) — Common-mistake #7 fix.
// SWAPPED QK^T (mfma(K,Q)); softmax fully in-register (2 shfl_xor);
// P->bf16 via v_cvt_pk_bf16_f32 + ds_write_b64; deferred normalization.
// ---------------------------------------------------------------------------
__global__ __launch_bounds__(256) void attn_k(const u16* __restrict__ Q,
                                              const u16* __restrict__ Kt,
                                              const u16* __restrict__ VT,
                                              u16* __restrict__ Y) {
  __shared__ __align__(16) short KsPs[256 * 64];  // K tile; reused as P (64x256)
  int tid = threadIdx.x;
  int t0 = blockIdx.x * 64, h = blockIdx.y, b = blockIdx.z;
  int wave = tid >> 6, lane = tid & 63;
  int l16 = lane & 15, quad = lane >> 4;
  int wb = wave * 16;

  // K stage: LDS chunk c = p*256+tid holds global chunk (n = c>>3, s^(n&7)).
#pragma unroll
  for (int p = 0; p < 8; ++p) {
    int c = p * 256 + tid;
    int n = c >> 3, s = c & 7;
    GLOAD_LDS16(Kt + ((size_t)(b * 256 + n)) * 1024 + h * 64 + ((s ^ (n & 7)) * 8),
                KsPs + (p * 256 + wave * 64) * 8);
  }
  const u16* qrow = Q + ((size_t)(b * 4096 + t0 + wb + l16)) * 1024 + h * 64;
  bf16x8 qf0 = *(const bf16x8*)(qrow + quad * 8);
  bf16x8 qf1 = *(const bf16x8*)(qrow + 32 + quad * 8);
  asm volatile("s_waitcnt vmcnt(0)" ::: "memory");
  __syncthreads();

  // swapped QK^T: sa[mt][r] = S[token=16mt+4quad+r][qrow=wb+l16]
  f32x4 sa[16];
#pragma unroll
  for (int mt = 0; mt < 16; ++mt)
#pragma unroll
    for (int r = 0; r < 4; ++r) sa[mt][r] = 0.f;
#pragma unroll
  for (int ks = 0; ks < 2; ++ks) {
    bf16x8 qb = ks ? qf1 : qf0;
#pragma unroll
    for (int mt = 0; mt < 16; ++mt) {
      int n = mt * 16 + l16;
      bf16x8 kf = *(const bf16x8*)&KsPs[n * 64 + (((ks * 4 + quad) ^ (n & 7)) * 8)];
      sa[mt] = __builtin_amdgcn_mfma_f32_16x16x32_bf16(kf, qb, sa[mt], 0, 0, 0);
    }
  }
  __syncthreads();  // all waves done reading K before P overwrites it

  // in-register softmax: lane's 64 tokens + cross-quad combine (lane^16,^32)
  const float CLG = 0.18033688011112042f;  // 0.125 * log2(e)
  float mx = -3.0e38f;
#pragma unroll
  for (int mt = 0; mt < 16; ++mt)
#pragma unroll
    for (int r = 0; r < 4; ++r) mx = fmaxf(mx, sa[mt][r]);
  mx = fmaxf(mx, __shfl_xor(mx, 16));
  mx = fmaxf(mx, __shfl_xor(mx, 32));
  float mxc = mx * CLG;
  float sum = 0.f;
#pragma unroll
  for (int mt = 0; mt < 16; ++mt)
#pragma unroll
    for (int r = 0; r < 4; ++r) {
      float e = __builtin_exp2f(sa[mt][r] * CLG - mxc);
      sa[mt][r] = e;
      sum += e;
    }
  sum += __shfl_xor(sum, 16);
  sum += __shfl_xor(sum, 32);
  float rsc = 1.0f / sum;

  // pack + vector store: row wb+l16; tokens 16mt+4quad+r -> chunk 2mt+(quad>>1),
  // stored at (chunk ^ (row&7)); in-chunk offset (quad&1)*4 + r.
  {
    int prow = wb + l16;
    short* pb = &KsPs[prow * 256 + (quad & 1) * 4];
    int q2 = quad >> 1, swz = l16 & 7;
#pragma unroll
    for (int mt = 0; mt < 16; ++mt) {
      float a0 = sa[mt][0], a1 = sa[mt][1], a2 = sa[mt][2], a3 = sa[mt][3];
      unsigned plo, phi;
      asm("v_cvt_pk_bf16_f32 %0, %1, %2" : "=v"(plo) : "v"(a0), "v"(a1));
      asm("v_cvt_pk_bf16_f32 %0, %1, %2" : "=v"(phi) : "v"(a2), "v"(a3));
      uint2 pk; pk.x = plo; pk.y = phi;
      *(uint2*)(pb + (((2 * mt + q2) ^ swz) * 8)) = pk;
    }
  }
  __syncthreads();

  // PV: A = P (LDS), B = V^T fragments DIRECT from global (L2-resident).
  const u16* vb = VT + ((size_t)(b * 1024 + h * 64)) * 256;
  f32x4 ya[4];
#pragma unroll
  for (int j = 0; j < 4; ++j)
#pragma unroll
    for (int r = 0; r < 4; ++r) ya[j][r] = 0.f;
  int m = wb + l16;
#pragma unroll
  for (int kk = 0; kk < 8; ++kk) {
    bf16x8 af = *(const bf16x8*)&KsPs[m * 256 + (((kk * 4 + quad) ^ (m & 7)) * 8)];
#pragma unroll
    for (int j = 0; j < 4; ++j) {
      bf16x8 bfr = *(const bf16x8*)(vb + (size_t)(j * 16 + l16) * 256 + kk * 32 + quad * 8);
      ya[j] = __builtin_amdgcn_mfma_f32_16x16x32_bf16(af, bfr, ya[j], 0, 0, 0);
    }
  }
  // per-output-row 1/sum: row quad*4+r's rsc lives in lanes with l16=quad*4+r
  float rscv[4];
#pragma unroll
  for (int r = 0; r < 4; ++r) rscv[r] = __shfl(rsc, quad * 4 + r);
#pragma unroll
  for (int j = 0; j < 4; ++j)
#pragma unroll
    for (int r = 0; r < 4; ++r)
      Y[((size_t)(b * 4096 + t0 + wb + quad * 4 + r)) * 1024 + h * 64 + j * 16 + l16] =
          f2b(ya[j][r] * rscv[r]);
}

// ---------------------------------------------------------------------------
extern "C" void kernel_launch(void* const* d_in, const int* in_sizes, int n_in,
                              void* d_out, int out_size, void* d_ws, size_t ws_size,
                              hipStream_t stream) {
  const float* x       = (const float*)d_in[0];
  const float* xf      = (const float*)d_in[1];
  const float* emb     = (const float*)d_in[2];
  const float* norm_g  = (const float*)d_in[3];
  const float* norm_b  = (const float*)d_in[4];
  const float* tnorm_g = (const float*)d_in[5];
  const float* tnorm_b = (const float*)d_in[6];
  const float* Wq      = (const float*)d_in[7];
  const float* bq      = (const float*)d_in[8];
  const float* Wk      = (const float*)d_in[9];
  const float* bk      = (const float*)d_in[10];
  const float* Wv      = (const float*)d_in[11];
  const float* bv      = (const float*)d_in[12];
  const float* We      = (const float*)d_in[13];
  const float* be      = (const float*)d_in[14];
  const float* snorm_g = (const float*)d_in[15];
  const float* snorm_b = (const float*)d_in[16];
  const float* Wo      = (const float*)d_in[17];
  const float* bo      = (const float*)d_in[18];

  const size_t MB = 1024 * 1024;
  char* dout = (char*)d_out;
  u16* qbuf = (u16*)(dout);             // 32 MB bf16 Q (dead after attn)
  u16* wqt  = (u16*)(dout + 32 * MB);   // 2 MB   (dead after Q-GEMM)
  u16* wkt  = (u16*)(dout + 34 * MB);   // 1.5 MB (dead after K-GEMM)
  u16* wvt  = (u16*)(dout + 36 * MB);   // 1.5 MB (dead after V-GEMM)
  float* out = (float*)d_out;

  char* ws = (char*)d_ws;
  u16* big1 = (u16*)(ws);                        // 32 MB: LN(x) -> y -> s
  u16* xfn  = (u16*)(ws + 32 * MB);              // 1.5 MB
  u16* kws  = (u16*)(ws + 33 * MB + 512 * 1024); // 2 MB  (B,256,1024)
  u16* vtws = (u16*)(ws + 35 * MB + 512 * 1024); // 2 MB  (B,1024,256)
  u16* wot  = (u16*)(ws + 37 * MB + 512 * 1024); // 2 MB  (needed during final GEMM)
  float* embo = (float*)(ws + 39 * MB + 512 * 1024); // 32 KB f32

  transpose4_k<<<dim3(32, 32, 4), dim3(32, 8), 0, stream>>>(
      Wq, Wk, Wv, Wo, wqt, wkt, wvt, wot, embo);

  ln_k<<<16384, 256, 0, stream>>>(x, norm_g, norm_b, big1, 1024);
  ln_k<<<1024, 256, 0, stream>>>(xf, tnorm_g, tnorm_b, xfn, 768);

  gemm256_k<<<dim3(128, 4), 512, 0, stream>>>(big1, wqt, bq, nullptr, qbuf, nullptr, 16384, 1024, 1024, 0);
  kvproj_k<<<dim3(8, 8, 2), 256, 0, stream>>>(xfn, wkt, wvt, bk, bv, kws, vtws);

  emb_k<<<dim3(8, 4, 8), 256, 0, stream>>>(emb, We, be, embo);

  attn_k<<<dim3(64, 16, 4), 256, 0, stream>>>(qbuf, kws, vtws, big1);

  style_k<<<16384, 256, 0, stream>>>(big1, snorm_g, snorm_b, embo, big1);

  gemm256_k<<<dim3(128, 4), 512, 0, stream>>>(big1, wot, bo, x, nullptr, out, 16384, 1024, 1024, 2);
}

// Round 10
// 361.652 us; speedup vs baseline: 1.0694x; 1.0694x over previous
//
#include <hip/hip_runtime.h>

typedef unsigned short u16;
typedef short bf16x8 __attribute__((ext_vector_type(8)));
typedef float f32x4 __attribute__((ext_vector_type(4)));

// Problem constants: B=4, T=4096, D=1024, N=256, L=768, H=16, dh=64, TE=1024
// I/O dtype: float32 (per reference). Internal MFMA compute: bf16.

__device__ __forceinline__ float b2f(u16 u) {
  union { unsigned int u; float f; } x; x.u = ((unsigned int)u) << 16; return x.f;
}
__device__ __forceinline__ u16 f2b(float f) {
  union { float f; unsigned int u; } x; x.f = f;
  unsigned int u = x.u;
  return (u16)((u + 0x7FFFu + ((u >> 16) & 1u)) >> 16);  // RNE
}

// async global->LDS, 16B per lane. LDS dest = wave-uniform base + lane*16.
#define GLOAD_LDS16(g, l)                                                      \
  __builtin_amdgcn_global_load_lds(                                            \
      (const __attribute__((address_space(1))) unsigned int*)(g),              \
      (__attribute__((address_space(3))) unsigned int*)(l), 16, 0, 0)

// ---------------------------------------------------------------------------
// Fused: 4-way weight transpose (z<4) + LN(xf) (z==4) + embo zero-fill.
// grid (32, 32, 5), block (32,8).
// z<4: dst[C][R] = bf16(src[R][C]), C=1024, R in {1024,768}.
// z==4: row LayerNorm of xf (1024 rows x 768), f32 -> bf16 into xfn.
// ---------------------------------------------------------------------------
__global__ __launch_bounds__(256) void transpose4_k(
    const float* __restrict__ Wq, const float* __restrict__ Wk,
    const float* __restrict__ Wv, const float* __restrict__ Wo,
    u16* __restrict__ wqt, u16* __restrict__ wkt,
    u16* __restrict__ wvt, u16* __restrict__ wot,
    float* __restrict__ embo,
    const float* __restrict__ xf, const float* __restrict__ tg,
    const float* __restrict__ tb, u16* __restrict__ xfn) {
  if (blockIdx.z == 4) {
    // --- LN of xf: row = by*32 + bx, C = 768 ---
    int row = blockIdx.y * 32 + blockIdx.x;
    int tid = threadIdx.y * 32 + threadIdx.x;
    const float* p = xf + (size_t)row * 768;
    int i0 = tid * 4;
    bool act = i0 < 768;
    float v0 = 0.f, v1 = 0.f, v2 = 0.f, v3 = 0.f;
    if (act) {
      float4 u = *(const float4*)(p + i0);
      v0 = u.x; v1 = u.y; v2 = u.z; v3 = u.w;
    }
    float s = v0 + v1 + v2 + v3;
    float q = v0 * v0 + v1 * v1 + v2 * v2 + v3 * v3;
    __shared__ float red[8];
#pragma unroll
    for (int m = 32; m; m >>= 1) { s += __shfl_xor(s, m); q += __shfl_xor(q, m); }
    if ((tid & 63) == 0) { red[tid >> 6] = s; red[4 + (tid >> 6)] = q; }
    __syncthreads();
    s = red[0] + red[1] + red[2] + red[3];
    q = red[4] + red[5] + red[6] + red[7];
    const float invC = 1.0f / 768.0f;
    float mu = s * invC;
    float rs = rsqrtf(q * invC - mu * mu + 1e-5f);
    if (act) {
      float4 ug = *(const float4*)(tg + i0);
      float4 ub = *(const float4*)(tb + i0);
      ushort4 o;
      o.x = f2b((v0 - mu) * rs * ug.x + ub.x);
      o.y = f2b((v1 - mu) * rs * ug.y + ub.y);
      o.z = f2b((v2 - mu) * rs * ug.z + ub.z);
      o.w = f2b((v3 - mu) * rs * ug.w + ub.w);
      *(ushort4*)(xfn + (size_t)row * 768 + i0) = o;
    }
    return;
  }
  if (blockIdx.z == 0 && blockIdx.y == 0) {
    int idx = blockIdx.x * 256 + threadIdx.y * 32 + threadIdx.x;
    embo[idx] = 0.f;  // 32 blocks x 256 threads = 8192 = B*2D
  }
  const float* src; u16* dst; int R;
  switch (blockIdx.z) {
    case 0: src = Wq; dst = wqt; R = 1024; break;
    case 1: src = Wk; dst = wkt; R = 768;  break;
    case 2: src = Wv; dst = wvt; R = 768;  break;
    default: src = Wo; dst = wot; R = 1024; break;
  }
  int bx = blockIdx.x * 32, by = blockIdx.y * 32;
  if (by >= R) return;
  __shared__ float t[32][33];
  int x = threadIdx.x, y = threadIdx.y;
#pragma unroll
  for (int i = 0; i < 4; ++i)
    t[y * 4 + i][x] = src[(size_t)(by + y * 4 + i) * 1024 + bx + x];
  __syncthreads();
#pragma unroll
  for (int i = 0; i < 4; ++i)
    dst[(size_t)(bx + y * 4 + i) * R + by + x] = f2b(t[x][y * 4 + i]);
}

// ---------------------------------------------------------------------------
// Row LayerNorm, f32 in -> bf16 out. One block per row. C = 1024 (x).
// ---------------------------------------------------------------------------
__global__ __launch_bounds__(256) void ln_k(const float* __restrict__ in,
                                            const float* __restrict__ g,
                                            const float* __restrict__ bta,
                                            u16* __restrict__ out, int C) {
  int row = blockIdx.x, tid = threadIdx.x;
  const float* p = in + (size_t)row * C;
  int i0 = tid * 4;
  bool act = i0 < C;
  float v0 = 0.f, v1 = 0.f, v2 = 0.f, v3 = 0.f;
  if (act) {
    float4 u = *(const float4*)(p + i0);
    v0 = u.x; v1 = u.y; v2 = u.z; v3 = u.w;
  }
  float s = v0 + v1 + v2 + v3;
  float q = v0 * v0 + v1 * v1 + v2 * v2 + v3 * v3;
  __shared__ float red[8];
#pragma unroll
  for (int m = 32; m; m >>= 1) { s += __shfl_xor(s, m); q += __shfl_xor(q, m); }
  if ((tid & 63) == 0) { red[tid >> 6] = s; red[4 + (tid >> 6)] = q; }
  __syncthreads();
  s = red[0] + red[1] + red[2] + red[3];
  q = red[4] + red[5] + red[6] + red[7];
  float invC = 1.0f / (float)C;
  float mu = s * invC;
  float rs = rsqrtf(q * invC - mu * mu + 1e-5f);
  if (act) {
    float4 ug = *(const float4*)(g + i0);
    float4 ub = *(const float4*)(bta + i0);
    ushort4 o;
    o.x = f2b((v0 - mu) * rs * ug.x + ub.x);
    o.y = f2b((v1 - mu) * rs * ug.y + ub.y);
    o.z = f2b((v2 - mu) * rs * ug.z + ub.z);
    o.w = f2b((v3 - mu) * rs * ug.w + ub.w);
    *(ushort4*)(out + (size_t)row * C + i0) = o;
  }
}

// ---------------------------------------------------------------------------
// Stylization: out = bf16( silu( LN(y)*(1+scale_b) + shift_b ) ).
// y is HEAD-MAJOR [b][h][t][64] (attn output in qbuf); out is ROW-MAJOR in a
// DIFFERENT buffer (big1) — distinct src/dst buffers avoid the round-8
// cross-block layout-conversion race.
// ---------------------------------------------------------------------------
__global__ __launch_bounds__(256) void style_k(const u16* __restrict__ y,
                                               const float* __restrict__ g,
                                               const float* __restrict__ bta,
                                               const float* __restrict__ embo,
                                               u16* __restrict__ out) {
  int row = blockIdx.x, tid = threadIdx.x;
  int b = row >> 12;  // T=4096
  int t = row & 4095;
  int i0 = tid * 4;
  int h = i0 >> 6, c = i0 & 63;
  ushort4 u = *(const ushort4*)(y + ((size_t)((b * 16 + h) * 4096 + t)) * 64 + c);
  float v0 = b2f(u.x), v1 = b2f(u.y), v2 = b2f(u.z), v3 = b2f(u.w);
  float s = v0 + v1 + v2 + v3;
  float q = v0 * v0 + v1 * v1 + v2 * v2 + v3 * v3;
  __shared__ float red[8];
#pragma unroll
  for (int m = 32; m; m >>= 1) { s += __shfl_xor(s, m); q += __shfl_xor(q, m); }
  if ((tid & 63) == 0) { red[tid >> 6] = s; red[4 + (tid >> 6)] = q; }
  __syncthreads();
  s = red[0] + red[1] + red[2] + red[3];
  q = red[4] + red[5] + red[6] + red[7];
  const float invC = 1.0f / 1024.0f;
  float mu = s * invC;
  float rs = rsqrtf(q * invC - mu * mu + 1e-5f);
  float4 ug = *(const float4*)(g + i0);
  float4 ub = *(const float4*)(bta + i0);
  float4 sc = *(const float4*)(embo + b * 2048 + i0);
  float4 sh = *(const float4*)(embo + b * 2048 + 1024 + i0);
  float h0 = ((v0 - mu) * rs * ug.x + ub.x) * (1.0f + sc.x) + sh.x;
  float h1 = ((v1 - mu) * rs * ug.y + ub.y) * (1.0f + sc.y) + sh.y;
  float h2 = ((v2 - mu) * rs * ug.z + ub.z) * (1.0f + sc.z) + sh.z;
  float h3 = ((v3 - mu) * rs * ug.w + ub.w) * (1.0f + sc.w) + sh.w;
  ushort4 o;
  o.x = f2b(h0 / (1.0f + __expf(-h0)));
  o.y = f2b(h1 / (1.0f + __expf(-h1)));
  o.z = f2b(h2 / (1.0f + __expf(-h2)));
  o.w = f2b(h3 / (1.0f + __expf(-h3)));
  *(ushort4*)(out + (size_t)row * 1024 + i0) = o;
}

// ---------------------------------------------------------------------------
// Split-K emb projection: embo[b][j] += sum_{i in split} silu(emb[b][i])*We[i][j]
// grid (8, 4, 8). embo pre-zeroed by transpose4_k; split 0 adds the bias.
// ---------------------------------------------------------------------------
__global__ __launch_bounds__(256) void emb_k(const float* __restrict__ emb,
                                             const float* __restrict__ We,
                                             const float* __restrict__ be,
                                             float* __restrict__ embo) {
  int b = blockIdx.y, tid = threadIdx.x;
  int j = blockIdx.x * 256 + tid;
  int i0 = blockIdx.z * 128;
  __shared__ float se[128];
  if (tid < 128) {
    float v = emb[b * 1024 + i0 + tid];
    se[tid] = v / (1.0f + __expf(-v));
  }
  __syncthreads();
  float acc = (blockIdx.z == 0) ? be[j] : 0.f;
#pragma unroll 8
  for (int i = 0; i < 128; ++i) acc += se[i] * We[(size_t)(i0 + i) * 2048 + j];
  atomicAdd(&embo[b * 2048 + j], acc);
}

// ---------------------------------------------------------------------------
// Fused K+V projections (one launch, 128 blocks): 128x128 tile, m97 structure.
// A = xfn (1024x768). z=0 -> K into kws (row-major); z=1 -> V^T into vtws.
// ---------------------------------------------------------------------------
__global__ __launch_bounds__(256) void kvproj_k(const u16* __restrict__ A,
                                                const u16* __restrict__ WkT,
                                                const u16* __restrict__ WvT,
                                                const float* __restrict__ bk_,
                                                const float* __restrict__ bv_,
                                                u16* __restrict__ Ck,
                                                u16* __restrict__ Cv) {
  const int K = 768, Nn = 1024;
  const u16* Bt = blockIdx.z ? WvT : WkT;
  const float* bias = blockIdx.z ? bv_ : bk_;
  __shared__ __align__(16) short As[128 * 64];
  __shared__ __align__(16) short Bs[128 * 64];
  int tid = threadIdx.x;
  int m0 = blockIdx.x * 128, n0 = blockIdx.y * 128;
  int wave = tid >> 6, lane = tid & 63;
  int l16 = lane & 15, quad = lane >> 4;
  int wm = (wave >> 1) * 64, wn = (wave & 1) * 64;

  f32x4 acc[4][4];
#pragma unroll
  for (int i = 0; i < 4; ++i)
#pragma unroll
    for (int j = 0; j < 4; ++j)
#pragma unroll
      for (int r = 0; r < 4; ++r) acc[i][j][r] = 0.f;

  for (int kt = 0; kt < K; kt += 64) {
#pragma unroll
    for (int p = 0; p < 4; ++p) {
      int c = p * 256 + tid;
      int r = c >> 3;
      int cd = ((c & 7) ^ (r & 7)) * 8;
      int lb = (p * 256 + wave * 64) * 8;
      GLOAD_LDS16(A + (size_t)(m0 + r) * K + kt + cd, As + lb);
      GLOAD_LDS16(Bt + (size_t)(n0 + r) * K + kt + cd, Bs + lb);
    }
    __syncthreads();
#pragma unroll
    for (int ks = 0; ks < 2; ++ks) {
      int swz = ((ks * 4 + quad) ^ (l16 & 7)) * 8;
      bf16x8 af[4], bfr[4];
#pragma unroll
      for (int i = 0; i < 4; ++i)
        af[i] = *(const bf16x8*)&As[(wm + i * 16 + l16) * 64 + swz];
#pragma unroll
      for (int j = 0; j < 4; ++j)
        bfr[j] = *(const bf16x8*)&Bs[(wn + j * 16 + l16) * 64 + swz];
#pragma unroll
      for (int i = 0; i < 4; ++i)
#pragma unroll
        for (int j = 0; j < 4; ++j)
          acc[i][j] = __builtin_amdgcn_mfma_f32_16x16x32_bf16(af[i], bfr[j], acc[i][j], 0, 0, 0);
    }
    __syncthreads();
  }

#pragma unroll
  for (int j = 0; j < 4; ++j) {
    int col = n0 + wn + j * 16 + l16;
    float bv = bias[col];
#pragma unroll
    for (int i = 0; i < 4; ++i) {
      int row0 = m0 + wm + i * 16 + quad * 4;
#pragma unroll
      for (int r = 0; r < 4; ++r) {
        int row = row0 + r;
        float v = acc[i][j][r] + bv;
        if (blockIdx.z) {
          Cv[((size_t)((row >> 8) * 1024 + col)) * 256 + (row & 255)] = f2b(v);
        } else {
          Ck[(size_t)row * Nn + col] = f2b(v);
        }
      }
    }
  }
}

// ---------------------------------------------------------------------------
// 128x256-tile deep-pipelined GEMM, 2 blocks/CU. BK=32, triple-buffered LDS
// (72 KiB), 8 waves, counted vmcnt(3), depth-2 prefetch, one barrier/tile.
// Epilogue: coalesced LDS-transpose.
// mode 2: Cf = acc+bias+res (f32, row-major).
// mode 3: Cb = bf16(acc+bias) stored HEAD-MAJOR [b][h][t][64] (for attn Q).
// ---------------------------------------------------------------------------
__global__ __launch_bounds__(512, 4) void gemm256_k(const u16* __restrict__ A,
                                                    const u16* __restrict__ Bt,
                                                    const float* __restrict__ bias,
                                                    const float* __restrict__ res,
                                                    u16* __restrict__ Cb,
                                                    float* __restrict__ Cf,
                                                    int M, int Nn, int K, int mode) {
  __shared__ __align__(16) short smem[36864];  // 72 KiB: [A0 A1 A2 | B0 B1 B2]
  short* AsB = smem;            // 3 x 4096 shorts (128x32 each)
  short* BsB = smem + 12288;    // 3 x 8192 shorts (256x32 each)
  int tid = threadIdx.x;
  int m0 = blockIdx.x * 128, n0 = blockIdx.y * 256;
  int wave = tid >> 6, lane = tid & 63;
  int l16 = lane & 15, quad = lane >> 4;
  int wm = (wave >> 2) * 64;   // 2 row-wave groups
  int wn = (wave & 3) * 64;    // 4 col-wave groups

  size_t offA;
  {
    int r = tid >> 2;
    int cg = (tid & 3) ^ ((r >> 1) & 3);
    offA = (size_t)(m0 + r) * K + cg * 8;
  }
  int ldsA = tid * 8;
  size_t offB[2];
  int ldsB[2];
#pragma unroll
  for (int p = 0; p < 2; ++p) {
    int c = p * 512 + tid;
    int r = c >> 2;
    int cg = (c & 3) ^ ((r >> 1) & 3);
    offB[p] = (size_t)(n0 + r) * K + cg * 8;
    ldsB[p] = c * 8;
  }

  int aoff[4], boff[4];
#pragma unroll
  for (int mi = 0; mi < 4; ++mi) {
    int R = wm + mi * 16 + l16;
    aoff[mi] = R * 32 + ((quad ^ ((R >> 1) & 3)) * 8);
  }
#pragma unroll
  for (int ni = 0; ni < 4; ++ni) {
    int R = wn + ni * 16 + l16;
    boff[ni] = R * 32 + ((quad ^ ((R >> 1) & 3)) * 8);
  }

  f32x4 acc[4][4];
#pragma unroll
  for (int i = 0; i < 4; ++i)
#pragma unroll
    for (int j = 0; j < 4; ++j)
#pragma unroll
      for (int r = 0; r < 4; ++r) acc[i][j][r] = 0.f;

#define STAGE(tt, bufc)                                                        \
  do {                                                                         \
    int kt_ = (tt) * 32;                                                       \
    GLOAD_LDS16(A + offA + kt_, AsB + (bufc) * 4096 + ldsA);                   \
    GLOAD_LDS16(Bt + offB[0] + kt_, BsB + (bufc) * 8192 + ldsB[0]);            \
    GLOAD_LDS16(Bt + offB[1] + kt_, BsB + (bufc) * 8192 + ldsB[1]);            \
  } while (0)

#define COMPUTE(curc)                                                          \
  do {                                                                         \
    const short* as_ = AsB + (curc) * 4096;                                    \
    const short* bs_ = BsB + (curc) * 8192;                                    \
    bf16x8 af[4], bfv[4];                                                      \
    _Pragma("unroll") for (int mi = 0; mi < 4; ++mi)                           \
        af[mi] = *(const bf16x8*)&as_[aoff[mi]];                               \
    _Pragma("unroll") for (int ni = 0; ni < 4; ++ni)                           \
        bfv[ni] = *(const bf16x8*)&bs_[boff[ni]];                              \
    __builtin_amdgcn_s_setprio(1);                                             \
    _Pragma("unroll") for (int mi = 0; mi < 4; ++mi)                           \
      _Pragma("unroll") for (int ni = 0; ni < 4; ++ni)                         \
        acc[mi][ni] = __builtin_amdgcn_mfma_f32_16x16x32_bf16(                 \
            af[mi], bfv[ni], acc[mi][ni], 0, 0, 0);                            \
    __builtin_amdgcn_s_setprio(0);                                             \
  } while (0)

  const int NT = K >> 5;  // 32 for K=1024
  STAGE(0, 0);
  STAGE(1, 1);

  int cur = 0;
  for (int t = 0; t < NT - 1; ++t) {
    asm volatile("s_waitcnt vmcnt(3)" ::: "memory");
    __builtin_amdgcn_s_barrier();
    asm volatile("" ::: "memory");
    if (t + 2 < NT) {
      int nb = cur + 2; if (nb >= 3) nb -= 3;
      STAGE(t + 2, nb);
    }
    COMPUTE(cur);
    cur = (cur == 2) ? 0 : cur + 1;
  }
  asm volatile("s_waitcnt vmcnt(0)" ::: "memory");
  __builtin_amdgcn_s_barrier();
  asm volatile("" ::: "memory");
  COMPUTE(cur);
#undef COMPUTE
#undef STAGE

  // coalesced epilogue via LDS transpose (f32[64][256] view, 2 chunks)
  float* eps = (float*)smem;
  float bv[4];
#pragma unroll
  for (int ni = 0; ni < 4; ++ni) bv[ni] = bias[n0 + wn + ni * 16 + l16];

#pragma unroll
  for (int half = 0; half < 2; ++half) {
    __syncthreads();
    if ((wave >> 2) == half) {
#pragma unroll
      for (int mi = 0; mi < 4; ++mi) {
#pragma unroll
        for (int ni = 0; ni < 4; ++ni) {
          int col = wn + ni * 16 + l16;
#pragma unroll
          for (int r = 0; r < 4; ++r) {
            int row = mi * 16 + quad * 4 + r;
            eps[row * 256 + (col ^ (((row >> 2) & 3) << 3))] =
                acc[mi][ni][r] + bv[ni];
          }
        }
      }
    }
    __syncthreads();
#pragma unroll
    for (int p = 0; p < 8; ++p) {
      int row = wave * 8 + p;
      int grow = m0 + half * 64 + row;
      int colb = (lane * 4) ^ (((row >> 2) & 3) << 3);
      f32x4 v = *(const f32x4*)&eps[row * 256 + colb];
      if (mode == 2) {
        float4 rv = ((const float4*)&res[(size_t)grow * Nn + n0])[lane];
        float4 o;
        o.x = v[0] + rv.x; o.y = v[1] + rv.y;
        o.z = v[2] + rv.z; o.w = v[3] + rv.w;
        ((float4*)&Cf[(size_t)grow * Nn + n0])[lane] = o;
      } else {
        ushort4 o;
        o.x = f2b(v[0]); o.y = f2b(v[1]); o.z = f2b(v[2]); o.w = f2b(v[3]);
        if (mode == 3) {
          // head-major: [b][h][t][64]; col0 = n0 + lane*4
          int col0 = n0 + lane * 4;
          int hh = col0 >> 6, cc = col0 & 63;
          int bb = grow >> 12, tt = grow & 4095;
          *(ushort4*)(Cb + ((size_t)((bb * 16 + hh) * 4096 + tt)) * 64 + cc) = o;
        } else {
          ((ushort4*)&Cb[(size_t)grow * Nn + n0])[lane] = o;
        }
      }
    }
  }
}

// ---------------------------------------------------------------------------
// Cross-attention: per (b,h), 64 Q-rows per block (4 waves x 16 rows).
// LDS = 64 KB: K tile (reused as P, then Y-bounce) + V^T tile. Both K and V
// staged via global_load_lds (pre-swizzled source, linear dest).
// Q is HEAD-MAJOR [b][h][t][64] -> 2KB contiguous wave reads.
// Y written IN-PLACE over Q (same head-major slots): each block reads only
// its own Q rows (drained by vmcnt(0) before compute) and writes Y to
// exactly those rows — no cross-block sharing, race-free.
// SWAPPED QK^T (mfma(K,Q)); in-register softmax (2 shfl_xor); P->bf16 via
// v_cvt_pk_bf16_f32 + ds_write_b64; deferred normalization.
// ---------------------------------------------------------------------------
__global__ __launch_bounds__(256) void attn_k(const u16* __restrict__ Q,
                                              const u16* __restrict__ Kt,
                                              const u16* __restrict__ VT,
                                              u16* __restrict__ Y) {
  __shared__ __align__(16) short KsPs[256 * 64];  // K tile; reused as P; Y bounce
  __shared__ __align__(16) short Vt[64 * 256];    // V^T tile: [d][token]
  int tid = threadIdx.x;
  int t0 = blockIdx.x * 64, h = blockIdx.y, b = blockIdx.z;
  int wave = tid >> 6, lane = tid & 63;
  int l16 = lane & 15, quad = lane >> 4;
  int wb = wave * 16;

  // K stage: LDS chunk c holds global chunk (n=c>>3, (c&7)^(n&7)).
#pragma unroll
  for (int p = 0; p < 8; ++p) {
    int c = p * 256 + tid;
    int n = c >> 3, s = c & 7;
    GLOAD_LDS16(Kt + ((size_t)(b * 256 + n)) * 1024 + h * 64 + ((s ^ (n & 7)) * 8),
                KsPs + (p * 256 + wave * 64) * 8);
  }
  // V stage: LDS chunk c holds global chunk (d=c>>5, (c&31)^(d&7)).
#pragma unroll
  for (int p = 0; p < 8; ++p) {
    int c = p * 256 + tid;
    int d = c >> 5, ch = c & 31;
    GLOAD_LDS16(VT + ((size_t)(b * 1024 + h * 64 + d)) * 256 + ((ch ^ (d & 7)) * 8),
                Vt + (p * 256 + wave * 64) * 8);
  }
  // Q (head-major): rows contiguous 128B; wave reads 2KB contiguous.
  const u16* qrow = Q + ((size_t)((b * 16 + h) * 4096 + t0 + wb + l16)) * 64;
  bf16x8 qf0 = *(const bf16x8*)(qrow + quad * 8);
  bf16x8 qf1 = *(const bf16x8*)(qrow + 32 + quad * 8);
  asm volatile("s_waitcnt vmcnt(0)" ::: "memory");
  __syncthreads();

  // swapped QK^T: sa[mt][r] = S[token=16mt+4quad+r][qrow=wb+l16]
  f32x4 sa[16];
#pragma unroll
  for (int mt = 0; mt < 16; ++mt)
#pragma unroll
    for (int r = 0; r < 4; ++r) sa[mt][r] = 0.f;
#pragma unroll
  for (int ks = 0; ks < 2; ++ks) {
    bf16x8 qb = ks ? qf1 : qf0;
#pragma unroll
    for (int mt = 0; mt < 16; ++mt) {
      int n = mt * 16 + l16;
      bf16x8 kf = *(const bf16x8*)&KsPs[n * 64 + (((ks * 4 + quad) ^ (n & 7)) * 8)];
      sa[mt] = __builtin_amdgcn_mfma_f32_16x16x32_bf16(kf, qb, sa[mt], 0, 0, 0);
    }
  }
  __syncthreads();  // all waves done reading K before P overwrites it

  // in-register softmax: lane's 64 tokens + cross-quad combine (lane^16,^32)
  const float CLG = 0.18033688011112042f;  // 0.125 * log2(e)
  float mx = -3.0e38f;
#pragma unroll
  for (int mt = 0; mt < 16; ++mt)
#pragma unroll
    for (int r = 0; r < 4; ++r) mx = fmaxf(mx, sa[mt][r]);
  mx = fmaxf(mx, __shfl_xor(mx, 16));
  mx = fmaxf(mx, __shfl_xor(mx, 32));
  float mxc = mx * CLG;
  float sum = 0.f;
#pragma unroll
  for (int mt = 0; mt < 16; ++mt)
#pragma unroll
    for (int r = 0; r < 4; ++r) {
      float e = __builtin_exp2f(sa[mt][r] * CLG - mxc);
      sa[mt][r] = e;
      sum += e;
    }
  sum += __shfl_xor(sum, 16);
  sum += __shfl_xor(sum, 32);
  float rsc = 1.0f / sum;

  // pack + vector store: row wb+l16; tokens 16mt+4quad+r -> chunk 2mt+(quad>>1),
  // stored at (chunk ^ (row&7)); in-chunk offset (quad&1)*4 + r.
  {
    int prow = wb + l16;
    short* pb = &KsPs[prow * 256 + (quad & 1) * 4];
    int q2 = quad >> 1, swz = l16 & 7;
#pragma unroll
    for (int mt = 0; mt < 16; ++mt) {
      float a0 = sa[mt][0], a1 = sa[mt][1], a2 = sa[mt][2], a3 = sa[mt][3];
      unsigned plo, phi;
      asm("v_cvt_pk_bf16_f32 %0, %1, %2" : "=v"(plo) : "v"(a0), "v"(a1));
      asm("v_cvt_pk_bf16_f32 %0, %1, %2" : "=v"(phi) : "v"(a2), "v"(a3));
      uint2 pk; pk.x = plo; pk.y = phi;
      *(uint2*)(pb + (((2 * mt + q2) ^ swz) * 8)) = pk;
    }
  }
  __syncthreads();

  f32x4 ya[4];
#pragma unroll
  for (int j = 0; j < 4; ++j)
#pragma unroll
    for (int r = 0; r < 4; ++r) ya[j][r] = 0.f;
  int m = wb + l16;
#pragma unroll
  for (int kk = 0; kk < 8; ++kk) {
    bf16x8 af = *(const bf16x8*)&KsPs[m * 256 + (((kk * 4 + quad) ^ (m & 7)) * 8)];
#pragma unroll
    for (int j = 0; j < 4; ++j) {
      int d = j * 16 + l16;
      bf16x8 bfr = *(const bf16x8*)&Vt[d * 256 + (((kk * 4 + quad) ^ (d & 7)) * 8)];
      ya[j] = __builtin_amdgcn_mfma_f32_16x16x32_bf16(af, bfr, ya[j], 0, 0, 0);
    }
  }
  // per-output-row 1/sum: row quad*4+r's rsc lives in lanes with l16=quad*4+r
  float rscv[4];
#pragma unroll
  for (int r = 0; r < 4; ++r) rscv[r] = __shfl(rsc, quad * 4 + r);

  // Y bounce through wave-private P rows (wb..wb+15), group-swizzled:
  // logical col group g = col>>3; stored at (g ^ (row>>2)&3)*8 + (col&7).
#pragma unroll
  for (int j = 0; j < 4; ++j)
#pragma unroll
    for (int r = 0; r < 4; ++r) {
      int lr = quad * 4 + r;
      int col = j * 16 + l16;
      int g = (col >> 3) ^ quad;  // quad == (lr>>2)&3
      KsPs[(wb + lr) * 256 + g * 8 + (col & 7)] = (short)f2b(ya[j][r] * rscv[r]);
    }
  // readback (wave-private, in-order DS => no barrier) + 2KB-contiguous store
  {
    int lr2 = lane >> 2;             // 0..15
    int sw = (lr2 >> 2) & 3;
    int g0 = (lane & 3) * 2;
    const short* yr = &KsPs[(wb + lr2) * 256];
    bf16x8 y0 = *(const bf16x8*)&yr[(g0 ^ sw) * 8];
    bf16x8 y1 = *(const bf16x8*)&yr[((g0 + 1) ^ sw) * 8];
    u16* yg = Y + ((size_t)((b * 16 + h) * 4096 + t0 + wb + lr2)) * 64 + (lane & 3) * 16;
    *(bf16x8*)yg = y0;
    *(bf16x8*)(yg + 8) = y1;
  }
}

// ---------------------------------------------------------------------------
extern "C" void kernel_launch(void* const* d_in, const int* in_sizes, int n_in,
                              void* d_out, int out_size, void* d_ws, size_t ws_size,
                              hipStream_t stream) {
  const float* x       = (const float*)d_in[0];
  const float* xf      = (const float*)d_in[1];
  const float* emb     = (const float*)d_in[2];
  const float* norm_g  = (const float*)d_in[3];
  const float* norm_b  = (const float*)d_in[4];
  const float* tnorm_g = (const float*)d_in[5];
  const float* tnorm_b = (const float*)d_in[6];
  const float* Wq      = (const float*)d_in[7];
  const float* bq      = (const float*)d_in[8];
  const float* Wk      = (const float*)d_in[9];
  const float* bk      = (const float*)d_in[10];
  const float* Wv      = (const float*)d_in[11];
  const float* bv      = (const float*)d_in[12];
  const float* We      = (const float*)d_in[13];
  const float* be      = (const float*)d_in[14];
  const float* snorm_g = (const float*)d_in[15];
  const float* snorm_b = (const float*)d_in[16];
  const float* Wo      = (const float*)d_in[17];
  const float* bo      = (const float*)d_in[18];

  const size_t MB = 1024 * 1024;
  char* dout = (char*)d_out;
  u16* qbuf = (u16*)(dout);             // 32 MB bf16 Q head-major; attn writes
                                        // Y in-place here (dead after style)
  u16* wqt  = (u16*)(dout + 32 * MB);   // 2 MB   (dead after Q-GEMM)
  u16* wkt  = (u16*)(dout + 34 * MB);   // 1.5 MB (dead after K-GEMM)
  u16* wvt  = (u16*)(dout + 36 * MB);   // 1.5 MB (dead after V-GEMM)
  float* out = (float*)d_out;

  char* ws = (char*)d_ws;
  u16* big1 = (u16*)(ws);                        // 32 MB: LN(x) -> s
  u16* xfn  = (u16*)(ws + 32 * MB);              // 1.5 MB
  u16* kws  = (u16*)(ws + 33 * MB + 512 * 1024); // 2 MB  (B,256,1024)
  u16* vtws = (u16*)(ws + 35 * MB + 512 * 1024); // 2 MB  (B,1024,256)
  u16* wot  = (u16*)(ws + 37 * MB + 512 * 1024); // 2 MB  (needed during final GEMM)
  float* embo = (float*)(ws + 39 * MB + 512 * 1024); // 32 KB f32

  // weight transposes + LN(xf) + embo zero-fill, one launch
  transpose4_k<<<dim3(32, 32, 5), dim3(32, 8), 0, stream>>>(
      Wq, Wk, Wv, Wo, wqt, wkt, wvt, wot, embo, xf, tnorm_g, tnorm_b, xfn);

  ln_k<<<16384, 256, 0, stream>>>(x, norm_g, norm_b, big1, 1024);

  // Q projection -> head-major qbuf (mode 3)
  gemm256_k<<<dim3(128, 4), 512, 0, stream>>>(big1, wqt, bq, nullptr, qbuf, nullptr, 16384, 1024, 1024, 3);
  kvproj_k<<<dim3(8, 8, 2), 256, 0, stream>>>(xfn, wkt, wvt, bk, bv, kws, vtws);

  emb_k<<<dim3(8, 4, 8), 256, 0, stream>>>(emb, We, be, embo);

  // attention: head-major Q in, Y written IN-PLACE over Q (qbuf)
  attn_k<<<dim3(64, 16, 4), 256, 0, stream>>>(qbuf, kws, vtws, qbuf);

  // stylization: head-major y (qbuf) -> row-major s (big1). Distinct buffers.
  style_k<<<16384, 256, 0, stream>>>(qbuf, snorm_g, snorm_b, embo, big1);

  gemm256_k<<<dim3(128, 4), 512, 0, stream>>>(big1, wot, bo, x, nullptr, out, 16384, 1024, 1024, 2);
}